// Round 2
// baseline (760.312 us; speedup 1.0000x reference)
//
#include <hip/hip_runtime.h>
#include <math.h>

#define S_LEN   2048
#define NHEADS  12
#define HD      128
#define DMODEL  1536
#define NBATCH  2

typedef __bf16 bf16x8 __attribute__((ext_vector_type(8)));
typedef float  f32x4  __attribute__((ext_vector_type(4)));
typedef unsigned short u16x8 __attribute__((ext_vector_type(8)));
typedef unsigned short u16x4 __attribute__((ext_vector_type(4)));

// ALiBi slopes for n=12 heads: pow2_slopes(8) + pow2_slopes(16)[0::2][:4]
__constant__ float c_slopes[NHEADS] = {
    0.5f, 0.25f, 0.125f, 0.0625f, 0.03125f, 0.015625f, 0.0078125f, 0.00390625f,
    0.70710678118654752f, 0.35355339059327379f,
    0.17677669529663689f, 0.08838834764831845f
};

__device__ __forceinline__ unsigned short f2bf(float x) {
    unsigned int u = __float_as_uint(x);
    u += 0x7FFFu + ((u >> 16) & 1u);   // round-to-nearest-even (no NaN inputs here)
    return (unsigned short)(u >> 16);
}
__device__ __forceinline__ float bf2f(unsigned short h) {
    return __uint_as_float(((unsigned int)h) << 16);
}
__device__ __forceinline__ void splitf(float v, unsigned short &h, unsigned short &l) {
    h = f2bf(v);
    l = f2bf(v - bf2f(h));
}
__device__ __forceinline__ f32x4 mfma16(bf16x8 a, bf16x8 b, f32x4 c) {
    return __builtin_amdgcn_mfma_f32_16x16x32_bf16(a, b, c, 0, 0, 0);
}

// ---------------------------------------------------------------------------
// RoPE cos/sin tables [S][64], fp32, computed to match jnp's fp32 pipeline.
// ---------------------------------------------------------------------------
__global__ void rope_table_kernel(float* __restrict__ cosT, float* __restrict__ sinT) {
    const int s = blockIdx.x;
    const int i = threadIdx.x;                       // 0..63
    double inv = exp(-((double)i / 64.0) * 9.210340371976184);  // 10000^(-i/64)
    float argf = (float)s * (float)inv;              // fp32 product like jnp.outer
    double a = (double)argf;
    cosT[s * 64 + i] = (float)cos(a);
    sinT[s * 64 + i] = (float)sin(a);
}

// ---------------------------------------------------------------------------
// Tiled transpose: (BH, S, HD) -> (BH, HD, S) for both hi and lo arrays.
// 64x64 tiles; LDS stride 65 (odd) -> scalar writes conflict-free, scalar
// reads ~2-way (free). Vector 16B on the global side both directions.
// ---------------------------------------------------------------------------
__global__ __launch_bounds__(256, 4)
void transpose_vt_kernel(const unsigned short* __restrict__ inH,
                         const unsigned short* __restrict__ inL,
                         unsigned short* __restrict__ outH,
                         unsigned short* __restrict__ outL)
{
    __shared__ unsigned short Th[64 * 65], Tl[64 * 65];
    const int tid = threadIdx.x;
    const int sx = blockIdx.x * 64, dx = blockIdx.y * 64;
    const int bh = blockIdx.z;
    const size_t ibase = (size_t)bh * S_LEN * HD;
    const size_t obase = (size_t)bh * HD * S_LEN;

#pragma unroll
    for (int t = 0; t < 2; t++) {
        int srow = (tid >> 3) + 32 * t;
        int c8 = tid & 7;
        u16x8 vh = *(const u16x8*)(inH + ibase + (size_t)(sx + srow) * HD + dx + c8 * 8);
        u16x8 vl = *(const u16x8*)(inL + ibase + (size_t)(sx + srow) * HD + dx + c8 * 8);
#pragma unroll
        for (int j = 0; j < 8; j++) {
            Th[(c8 * 8 + j) * 65 + srow] = vh[j];
            Tl[(c8 * 8 + j) * 65 + srow] = vl[j];
        }
    }
    __syncthreads();
#pragma unroll
    for (int t = 0; t < 2; t++) {
        int drow = (tid >> 3) + 32 * t;
        int c8 = tid & 7;
        u16x8 vh, vl;
#pragma unroll
        for (int j = 0; j < 8; j++) {
            vh[j] = Th[drow * 65 + c8 * 8 + j];
            vl[j] = Tl[drow * 65 + c8 * 8 + j];
        }
        *(u16x8*)(outH + obase + (size_t)(dx + drow) * S_LEN + sx + c8 * 8) = vh;
        *(u16x8*)(outL + obase + (size_t)(dx + drow) * S_LEN + sx + c8 * 8) = vl;
    }
}

// ---------------------------------------------------------------------------
// Split-bf16 GEMM:  C[M][N] = A[MxK] @ W[NxK]^T + bias
// mode 0: write fp32 C row-major (final output projection)
// mode 1: QKV epilogue with RoPE  -> bf16 hi/lo arrays in (B,H,S,hd)
// mode 2: QKV epilogue, no RoPE   -> bf16 hi/lo arrays in (B,H,S,hd)
// ---------------------------------------------------------------------------
#define BM 128
#define BN 128
#define BK 32
#define LDT 40   // LDS row stride in bf16 elems (32 + 8 pad -> conflict-light)

__global__ __launch_bounds__(256, 2)
void gemm_split_kernel(const float* __restrict__ A, const float* __restrict__ W,
                       const float* __restrict__ bias,
                       int M, int N, int K,
                       float* __restrict__ outF,
                       unsigned short* __restrict__ outH, unsigned short* __restrict__ outL,
                       const float* __restrict__ cosT, const float* __restrict__ sinT,
                       int mode)
{
    __shared__ unsigned short Ah[BM * LDT], Al[BM * LDT];
    __shared__ unsigned short Bh[BN * LDT], Bl[BN * LDT];

    const int tid  = threadIdx.x;
    const int lane = tid & 63;
    const int wid  = tid >> 6;
    const int wm   = wid >> 1, wn = wid & 1;
    const int m0   = blockIdx.x * BM, n0 = blockIdx.y * BN;
    const int l15  = lane & 15, l4 = lane >> 4;
    const int kq   = l4 * 8;

    f32x4 acc[4][4] = {};

    float4 pa[4], pb[4];
    const int KT = K / BK;

    // prefetch tile 0
#pragma unroll
    for (int i = 0; i < 4; i++) {
        int q = tid + 256 * i;
        int row = q >> 3, c4 = q & 7;
        pa[i] = *(const float4*)(A + (size_t)(m0 + row) * K + c4 * 4);
        pb[i] = *(const float4*)(W + (size_t)(n0 + row) * K + c4 * 4);
    }

    for (int kt = 0; kt < KT; ++kt) {
        __syncthreads();
        // convert + stage into LDS (hi/lo split)
#pragma unroll
        for (int i = 0; i < 4; i++) {
            int q = tid + 256 * i;
            int row = q >> 3, c4 = q & 7;
            unsigned short h0, l0, h1, l1, h2, l2, h3, l3;
            splitf(pa[i].x, h0, l0); splitf(pa[i].y, h1, l1);
            splitf(pa[i].z, h2, l2); splitf(pa[i].w, h3, l3);
            u16x4 hv = {h0, h1, h2, h3};
            u16x4 lv = {l0, l1, l2, l3};
            *(u16x4*)&Ah[row * LDT + c4 * 4] = hv;
            *(u16x4*)&Al[row * LDT + c4 * 4] = lv;
            splitf(pb[i].x, h0, l0); splitf(pb[i].y, h1, l1);
            splitf(pb[i].z, h2, l2); splitf(pb[i].w, h3, l3);
            u16x4 hw = {h0, h1, h2, h3};
            u16x4 lw = {l0, l1, l2, l3};
            *(u16x4*)&Bh[row * LDT + c4 * 4] = hw;
            *(u16x4*)&Bl[row * LDT + c4 * 4] = lw;
        }
        __syncthreads();

        // prefetch next tile (loads fly during MFMA below)
        if (kt + 1 < KT) {
#pragma unroll
            for (int i = 0; i < 4; i++) {
                int q = tid + 256 * i;
                int row = q >> 3, c4 = q & 7;
                pa[i] = *(const float4*)(A + (size_t)(m0 + row) * K + (kt + 1) * BK + c4 * 4);
                pb[i] = *(const float4*)(W + (size_t)(n0 + row) * K + (kt + 1) * BK + c4 * 4);
            }
        }

        bf16x8 ah[4], al[4], bh[4], bl[4];
#pragma unroll
        for (int mi = 0; mi < 4; mi++) {
            int r = wm * 64 + mi * 16 + l15;
            ah[mi] = *(const bf16x8*)&Ah[r * LDT + kq];
            al[mi] = *(const bf16x8*)&Al[r * LDT + kq];
        }
#pragma unroll
        for (int ni = 0; ni < 4; ni++) {
            int r = wn * 64 + ni * 16 + l15;
            bh[ni] = *(const bf16x8*)&Bh[r * LDT + kq];
            bl[ni] = *(const bf16x8*)&Bl[r * LDT + kq];
        }
#pragma unroll
        for (int mi = 0; mi < 4; mi++) {
#pragma unroll
            for (int ni = 0; ni < 4; ni++) {
                acc[mi][ni] = mfma16(ah[mi], bh[ni], acc[mi][ni]);
                acc[mi][ni] = mfma16(ah[mi], bl[ni], acc[mi][ni]);
                acc[mi][ni] = mfma16(al[mi], bh[ni], acc[mi][ni]);
            }
        }
    }

    // epilogue
#pragma unroll
    for (int ni = 0; ni < 4; ni++) {
        int col = n0 + wn * 64 + ni * 16 + l15;
        float bv = bias[col];
        int hcol = col >> 7;            // head
        int d    = col & (HD - 1);      // dim within head
#pragma unroll
        for (int mi = 0; mi < 4; mi++) {
#pragma unroll
            for (int r = 0; r < 4; r++) {
                int row = m0 + wm * 64 + mi * 16 + l4 * 4 + r;
                float v = acc[mi][ni][r] + bv;
                if (mode == 0) {
                    outF[(size_t)row * N + col] = v;
                } else {
                    int bb = row >> 11;
                    int ss = row & (S_LEN - 1);
                    if (mode == 1) {
                        // RoPE on interleaved pairs (d even: te, d odd: to)
                        float p  = __shfl_xor(v, 1);
                        float cc = cosT[ss * 64 + (d >> 1)];
                        float sn = sinT[ss * 64 + (d >> 1)];
                        v = (d & 1) ? fmaf(p, sn, v * cc) : fmaf(-p, sn, v * cc);
                    }
                    unsigned short hh, ll;
                    splitf(v, hh, ll);
                    size_t o = ((size_t)(bb * NHEADS + hcol) * S_LEN + ss) * HD + d;
                    outH[o] = hh;
                    outL[o] = ll;
                }
            }
        }
    }
}

// ---------------------------------------------------------------------------
// Flash attention with ALiBi (non-causal), split-bf16 MFMA.
// Block = 4 waves x 16 q-rows = 64 q-rows per block; KBLK=32 keys/tile.
// V comes pre-transposed (B,H,hd,S) so staging is all 16B vector ops.
// ---------------------------------------------------------------------------
#define QB  64
#define KB  32
#define LKD 136   // K LDS stride (128 hd + 8 pad)
#define LVD 40    // V^T LDS stride (32 keys + 8 pad)
#define LPD 40    // P LDS stride (32 keys + 8 pad)

__global__ __launch_bounds__(256, 3)
void flash_kernel(const unsigned short* __restrict__ Qh, const unsigned short* __restrict__ Ql,
                  const unsigned short* __restrict__ Kh, const unsigned short* __restrict__ Kl,
                  const unsigned short* __restrict__ Vth_g, const unsigned short* __restrict__ Vtl_g,
                  float* __restrict__ outF /* (B,S,D) */)
{
    __shared__ unsigned short Ksh[KB * LKD], Ksl[KB * LKD];
    __shared__ unsigned short Vth[HD * LVD], Vtl[HD * LVD];
    __shared__ unsigned short Psh[4 * 16 * LPD], Psl[4 * 16 * LPD];

    const int tid  = threadIdx.x, lane = tid & 63, wid = tid >> 6;
    const int l15  = lane & 15, l4 = lane >> 4;
    const int kq   = l4 * 8;
    const int qt   = blockIdx.x, bh = blockIdx.y;
    const int b    = bh / NHEADS, h = bh % NHEADS;
    const float slope = c_slopes[h];
    const float scale = 0.088388347648318447f;   // 1/sqrt(128)

    const size_t base  = (size_t)bh * S_LEN * HD;   // (B,H,S,hd) arrays
    const size_t vbase = (size_t)bh * HD * S_LEN;   // (B,H,hd,S) arrays

    // Q fragments in registers (A-operand layout: m=l15, k-chunk by l4)
    bf16x8 qfh[4], qfl[4];
    {
        const int qrow = qt * QB + wid * 16 + l15;
#pragma unroll
        for (int ks = 0; ks < 4; ks++) {
            size_t o = base + (size_t)qrow * HD + ks * 32 + kq;
            qfh[ks] = *(const bf16x8*)(Qh + o);
            qfl[ks] = *(const bf16x8*)(Ql + o);
        }
    }

    float m_r[4], l_r[4];
#pragma unroll
    for (int r = 0; r < 4; r++) { m_r[r] = -1e30f; l_r[r] = 0.0f; }
    f32x4 oacc[8] = {};

    unsigned short* Pmh = &Psh[wid * 16 * LPD];
    unsigned short* Pml = &Psl[wid * 16 * LPD];

    for (int kt = 0; kt < S_LEN / KB; ++kt) {
        __syncthreads();
        // stage K [key][hd]: 16B vector ops only
#pragma unroll
        for (int i = 0; i < 2; i++) {
            int u = tid + 256 * i;
            int row = u >> 4, c8 = u & 15;
            size_t g = base + (size_t)(kt * KB + row) * HD + c8 * 8;
            *(u16x8*)&Ksh[row * LKD + c8 * 8] = *(const u16x8*)(Kh + g);
            *(u16x8*)&Ksl[row * LKD + c8 * 8] = *(const u16x8*)(Kl + g);
        }
        // stage V^T [hd][key] from pre-transposed global: 16B vector ops only
#pragma unroll
        for (int i = 0; i < 2; i++) {
            int u = tid + 256 * i;
            int row = (u >> 2) & 127;      // hd dim (two iters cover 128 rows)
            int c = u & 3;                  // key chunk of 8
            size_t g = vbase + (size_t)row * S_LEN + kt * KB + c * 8;
            *(u16x8*)&Vth[row * LVD + c * 8] = *(const u16x8*)(Vth_g + g);
            *(u16x8*)&Vtl[row * LVD + c * 8] = *(const u16x8*)(Vtl_g + g);
        }
        __syncthreads();

        // scores: D[q16 x key32] accumulated over hd=128
        f32x4 sc[2] = {};
#pragma unroll
        for (int ks = 0; ks < 4; ks++) {
#pragma unroll
            for (int nf = 0; nf < 2; nf++) {
                int krow = nf * 16 + l15;
                bf16x8 kh = *(const bf16x8*)&Ksh[krow * LKD + ks * 32 + kq];
                bf16x8 kl = *(const bf16x8*)&Ksl[krow * LKD + ks * 32 + kq];
                sc[nf] = mfma16(qfh[ks], kh, sc[nf]);
                sc[nf] = mfma16(qfh[ks], kl, sc[nf]);
                sc[nf] = mfma16(qfl[ks], kh, sc[nf]);
            }
        }

        // online softmax (row = l4*4 + r; keys spread over l15 x 2 frags)
#pragma unroll
        for (int r = 0; r < 4; r++) {
            float s0 = fmaf(sc[0][r], scale, slope * (float)(kt * KB + l15));
            float s1 = fmaf(sc[1][r], scale, slope * (float)(kt * KB + 16 + l15));
            float mx = fmaxf(s0, s1);
            mx = fmaxf(mx, __shfl_xor(mx, 1));
            mx = fmaxf(mx, __shfl_xor(mx, 2));
            mx = fmaxf(mx, __shfl_xor(mx, 4));
            mx = fmaxf(mx, __shfl_xor(mx, 8));
            float mnew = fmaxf(m_r[r], mx);
            float corr = __expf(m_r[r] - mnew);
            m_r[r] = mnew;
            float p0 = __expf(s0 - mnew);
            float p1 = __expf(s1 - mnew);
            sc[0][r] = p0;
            sc[1][r] = p1;
            float rs = p0 + p1;
            rs += __shfl_xor(rs, 1);
            rs += __shfl_xor(rs, 2);
            rs += __shfl_xor(rs, 4);
            rs += __shfl_xor(rs, 8);
            l_r[r] = l_r[r] * corr + rs;
#pragma unroll
            for (int nf = 0; nf < 8; nf++) oacc[nf][r] *= corr;
        }

        // P -> LDS (hi/lo), transposing C-layout to A-operand layout
#pragma unroll
        for (int nf = 0; nf < 2; nf++) {
#pragma unroll
            for (int r = 0; r < 4; r++) {
                unsigned short hh, ll;
                splitf(sc[nf][r], hh, ll);
                int row = l4 * 4 + r, col = nf * 16 + l15;
                Pmh[row * LPD + col] = hh;
                Pml[row * LPD + col] = ll;
            }
        }
        asm volatile("s_waitcnt lgkmcnt(0)" ::: "memory");
        __builtin_amdgcn_sched_barrier(0);

        // PV: O[q16 x hd128] += P[q16 x key32] @ V[key32 x hd]
        bf16x8 ph = *(const bf16x8*)&Pmh[l15 * LPD + kq];
        bf16x8 pl = *(const bf16x8*)&Pml[l15 * LPD + kq];
#pragma unroll
        for (int nf = 0; nf < 8; nf++) {
            int vrow = nf * 16 + l15;
            bf16x8 vh = *(const bf16x8*)&Vth[vrow * LVD + kq];
            bf16x8 vl = *(const bf16x8*)&Vtl[vrow * LVD + kq];
            oacc[nf] = mfma16(ph, vh, oacc[nf]);
            oacc[nf] = mfma16(ph, vl, oacc[nf]);
            oacc[nf] = mfma16(pl, vh, oacc[nf]);
        }
    }

    // epilogue: divide by l, write (B,S,D) fp32
#pragma unroll
    for (int r = 0; r < 4; r++) {
        float inv = 1.0f / l_r[r];
        int srow = qt * QB + wid * 16 + l4 * 4 + r;
        size_t ob = ((size_t)b * S_LEN + srow) * DMODEL + h * HD;
#pragma unroll
        for (int nf = 0; nf < 8; nf++) {
            outF[ob + nf * 16 + l15] = oacc[nf][r] * inv;
        }
    }
}

// ---------------------------------------------------------------------------
extern "C" void kernel_launch(void* const* d_in, const int* in_sizes, int n_in,
                              void* d_out, int out_size, void* d_ws, size_t ws_size,
                              hipStream_t stream)
{
    const float* x  = (const float*)d_in[0];
    const float* Wq = (const float*)d_in[1];
    const float* bq = (const float*)d_in[2];
    const float* Wk = (const float*)d_in[3];
    const float* bk = (const float*)d_in[4];
    const float* Wv = (const float*)d_in[5];
    const float* bv = (const float*)d_in[6];
    const float* Wo = (const float*)d_in[7];
    const float* bo = (const float*)d_in[8];
    float* out = (float*)d_out;

    char* ws = (char*)d_ws;
    const size_t n_qkv = (size_t)NBATCH * NHEADS * S_LEN * HD;   // 6,291,456 elems

    float* cosT = (float*)ws;  ws += (size_t)S_LEN * 64 * sizeof(float);
    float* sinT = (float*)ws;  ws += (size_t)S_LEN * 64 * sizeof(float);
    unsigned short* Qh = (unsigned short*)ws; ws += n_qkv * 2;
    unsigned short* Ql = (unsigned short*)ws; ws += n_qkv * 2;
    unsigned short* Kh = (unsigned short*)ws; ws += n_qkv * 2;
    unsigned short* Kl = (unsigned short*)ws; ws += n_qkv * 2;
    unsigned short* Vh = (unsigned short*)ws; ws += n_qkv * 2;   // also reused as attnO
    unsigned short* Vl = (unsigned short*)ws; ws += n_qkv * 2;
    unsigned short* Vth_g = (unsigned short*)ws; ws += n_qkv * 2;
    unsigned short* Vtl_g = (unsigned short*)ws; ws += n_qkv * 2;
    // attnO aliases Vh+Vl (25,165,824 B each side, exact fit); V data is dead
    // after the transpose kernel, and flash reads only Vth_g/Vtl_g.
    float* attnO = (float*)Vh;

    const int M = NBATCH * S_LEN;   // 4096

    rope_table_kernel<<<dim3(S_LEN), dim3(64), 0, stream>>>(cosT, sinT);

    dim3 gg(M / BM, DMODEL / BN);
    gemm_split_kernel<<<gg, 256, 0, stream>>>(x, Wq, bq, M, DMODEL, DMODEL,
                                              nullptr, Qh, Ql, cosT, sinT, 1);
    gemm_split_kernel<<<gg, 256, 0, stream>>>(x, Wk, bk, M, DMODEL, DMODEL,
                                              nullptr, Kh, Kl, cosT, sinT, 1);
    gemm_split_kernel<<<gg, 256, 0, stream>>>(x, Wv, bv, M, DMODEL, DMODEL,
                                              nullptr, Vh, Vl, cosT, sinT, 2);

    transpose_vt_kernel<<<dim3(S_LEN / 64, HD / 64, NBATCH * NHEADS), 256, 0, stream>>>(
        Vh, Vl, Vth_g, Vtl_g);

    flash_kernel<<<dim3(S_LEN / QB, NBATCH * NHEADS), 256, 0, stream>>>(
        Qh, Ql, Kh, Kl, Vth_g, Vtl_g, attnO);

    gemm_split_kernel<<<gg, 256, 0, stream>>>(attnO, Wo, bo, M, DMODEL, DMODEL,
                                              out, nullptr, nullptr, nullptr, nullptr, 0);
}